// Round 3
// baseline (6127.948 us; speedup 1.0000x reference)
//
#include <hip/hip_runtime.h>

// ---------------------------------------------------------------------------
// LSTM: out[t] = h_t for t in [0,256);  final (c,h) appended.
//   T=256, B=128, D=1024, U=1024, 4U=4096
// Chunked pipeline (16 x 16 steps), single-stream serialized, ws = 34MB:
//   k_fill      : beacon 777.0f over all of out (diagnostic; fully overwritten)
//   k_transpose : kernelx/kernelh f32 [1024][4096] -> W^T bf16 [4096][1024]
//   k_gemm_xz   : xz_chunk = inputs[t0..t0+16] @ kernelx  (bf16 MFMA)
//   k_scan      : PLAIN launch (not cooperative), 256 blocks = 256 CUs,
//                 1 block/CU; 8 groups x 32 blocks; block owns 16 batch rows
//                 x 32 hidden cols; Wh slice in VGPRs as MFMA B-frags;
//                 h exchanged via swizzled global buf + LDS; 1 group
//                 barrier/step (monotone-target atomic counter).
// ---------------------------------------------------------------------------

typedef float  f32x4 __attribute__((ext_vector_type(4)));
typedef float  f32x2 __attribute__((ext_vector_type(2)));
typedef __bf16 bf16x8 __attribute__((ext_vector_type(8)));
typedef unsigned short us8 __attribute__((ext_vector_type(8)));
typedef unsigned short us2 __attribute__((ext_vector_type(2)));

#define TT 256
#define BB 128
#define DD 1024
#define UU 1024
#define NZ 4096
#define CHUNK 16
#define NCHUNK 16

__device__ __forceinline__ unsigned short f2bf(float x) {
  union { float f; unsigned u; } v; v.f = x;
  unsigned r = v.u + 0x7fffu + ((v.u >> 16) & 1u);   // RNE
  return (unsigned short)(r >> 16);
}
__device__ __forceinline__ float bf2f(unsigned short b) {
  union { unsigned u; float f; } v; v.u = ((unsigned)b) << 16;
  return v.f;
}
__device__ __forceinline__ float sigm(float x) { return 1.f / (1.f + __expf(-x)); }
__device__ __forceinline__ float tanh_(float x) { return 1.f - 2.f / (__expf(2.f * x) + 1.f); }

// ---------------- beacon fill (diagnostic; k_scan overwrites all of out)
__global__ __launch_bounds__(256) void k_fill(float* __restrict__ p, int n) {
  for (int i = blockIdx.x * 256 + threadIdx.x; i < n; i += gridDim.x * 256)
    p[i] = 777.0f;
}

// ---------------- transpose+convert: in f32 [1024][4096] -> out bf16 [4096][1024]
__global__ __launch_bounds__(256) void k_transpose(const float* __restrict__ in,
                                                   unsigned short* __restrict__ out) {
  __shared__ unsigned short tile[64][72];
  const int ni = blockIdx.x;           // 64 tiles along N=4096
  const int ki = blockIdx.y;           // 16 tiles along K=1024
  const int t = threadIdx.x;
  const int c = t & 63, r0 = t >> 6;
#pragma unroll
  for (int rr = 0; rr < 16; ++rr) {
    int r = r0 * 16 + rr;              // k-row within tile
    tile[r][c] = f2bf(in[(size_t)(ki * 64 + r) * NZ + ni * 64 + c]);
  }
  __syncthreads();
  const int kcol = t & 63, ng = t >> 6;
#pragma unroll
  for (int cc = 0; cc < 16; ++cc) {
    int n_off = ng * 16 + cc;
    out[(size_t)(ni * 64 + n_off) * DD + ki * 64 + kcol] = tile[kcol][n_off];
  }
}

// ---------------- phase 1 (per chunk): xz[2048][4096] bf16 = A[2048][1024] @ kernelx
// A f32 row-major, Bt = WxT bf16 [4096][1024] (k contiguous). 128x128 tile, BK=64.
__global__ __launch_bounds__(256, 2) void k_gemm_xz(const float* __restrict__ A,
                                                    const unsigned short* __restrict__ Bt,
                                                    unsigned short* __restrict__ C) {
  __shared__ unsigned short Al[2][128][72];
  __shared__ unsigned short Bl[2][128][72];
  const int bx = blockIdx.x;
  const int tn = bx & 31, tm = bx >> 5;          // 32 n-tiles, 16 m-tiles
  const int tid = threadIdx.x;
  const int wave = tid >> 6, lane = tid & 63;
  const int wr = wave >> 1, wc = wave & 1;
  const int l15 = lane & 15, kg = lane >> 4;

  f32x4 acc[4][4] = {};
  float4 ra[4][2];
  us8 rb[4];

  auto load_tile = [&](int kt) {
#pragma unroll
    for (int q = 0; q < 4; ++q) {
      int eidx = (q * 256 + tid) * 8;
      int row = eidx >> 6, col = eidx & 63;
      const float* p = A + (size_t)(tm * 128 + row) * DD + kt * 64 + col;
      ra[q][0] = *(const float4*)p;
      ra[q][1] = *(const float4*)(p + 4);
      rb[q] = *(const us8*)(Bt + (size_t)(tn * 128 + row) * DD + kt * 64 + col);
    }
  };
  auto store_tile = [&](int buf) {
#pragma unroll
    for (int q = 0; q < 4; ++q) {
      int eidx = (q * 256 + tid) * 8;
      int row = eidx >> 6, col = eidx & 63;
      us8 v;
      v[0] = f2bf(ra[q][0].x); v[1] = f2bf(ra[q][0].y);
      v[2] = f2bf(ra[q][0].z); v[3] = f2bf(ra[q][0].w);
      v[4] = f2bf(ra[q][1].x); v[5] = f2bf(ra[q][1].y);
      v[6] = f2bf(ra[q][1].z); v[7] = f2bf(ra[q][1].w);
      *(us8*)&Al[buf][row][col] = v;
      *(us8*)&Bl[buf][row][col] = rb[q];
    }
  };

  load_tile(0);
  store_tile(0);
  __syncthreads();

  for (int kt = 0; kt < 16; ++kt) {
    const int buf = kt & 1;
    if (kt < 15) load_tile(kt + 1);
#pragma unroll
    for (int ks = 0; ks < 2; ++ks) {
      bf16x8 af[4], bfr[4];
#pragma unroll
      for (int mi = 0; mi < 4; ++mi)
        af[mi] = *(const bf16x8*)&Al[buf][wr * 64 + mi * 16 + l15][ks * 32 + kg * 8];
#pragma unroll
      for (int ni = 0; ni < 4; ++ni)
        bfr[ni] = *(const bf16x8*)&Bl[buf][wc * 64 + ni * 16 + l15][ks * 32 + kg * 8];
#pragma unroll
      for (int mi = 0; mi < 4; ++mi)
#pragma unroll
        for (int ni = 0; ni < 4; ++ni)
          acc[mi][ni] = __builtin_amdgcn_mfma_f32_16x16x32_bf16(af[mi], bfr[ni], acc[mi][ni], 0, 0, 0);
    }
    if (kt < 15) store_tile(buf ^ 1);
    __syncthreads();
  }

#pragma unroll
  for (int ni = 0; ni < 4; ++ni) {
    const size_t col = (size_t)tn * 128 + wc * 64 + ni * 16 + l15;
#pragma unroll
    for (int mi = 0; mi < 4; ++mi) {
#pragma unroll
      for (int j = 0; j < 4; ++j) {
        const size_t row = (size_t)tm * 128 + wr * 64 + mi * 16 + kg * 4 + j;
        C[row * NZ + col] = f2bf(acc[mi][ni][j]);
      }
    }
  }
}

// ---------------- phase 2: scan over one 16-step chunk (plain launch)
// 256 blocks x 256 threads, 1 block/CU. group g = blk&7, sb = blk>>3.
// Block owns batch rows [g*16, g*16+16) and hidden cols [sb*32, sb*32+32).
// wave = gate (i,f,o,u); each wave holds Wh B-frags for its 32 z-cols in regs.
__global__ __launch_bounds__(256, 1) void k_scan(const float* __restrict__ init_cs,
                                                 const int* __restrict__ masks,
                                                 const unsigned short* __restrict__ WhT,
                                                 const float* __restrict__ bias,
                                                 const unsigned short* __restrict__ xz,
                                                 float* __restrict__ out,
                                                 float* __restrict__ fin_cs,
                                                 unsigned short* __restrict__ hglob,
                                                 unsigned* __restrict__ bctr,
                                                 int t0) {
  __shared__ unsigned short hlds[16 * 1024];     // 32KB, swizzled layout
  __shared__ float zlds[4][16][33];

  const int tid = threadIdx.x;
  const int wave = tid >> 6, lane = tid & 63;
  const int l15 = lane & 15, kg = lane >> 4;
  const int blk = blockIdx.x;
  const int g = blk & 7;
  const int sb = blk >> 3;
  const int u0 = sb * 32;
  const int row0 = g * 16;
  unsigned* ctr = bctr + g * 32;                 // 128B apart per group

  // ---- Wh fragments resident in registers: w0/w1[ks]
  bf16x8 w0[32], w1[32];
  {
    const size_t r0 = (size_t)(wave * UU + u0 + l15) * DD;
    const size_t r1 = (size_t)(wave * UU + u0 + 16 + l15) * DD;
#pragma unroll
    for (int ks = 0; ks < 32; ++ks) {
      w0[ks] = *(const bf16x8*)(WhT + r0 + ks * 32 + kg * 8);
      w1[ks] = *(const bf16x8*)(WhT + r1 + ks * 32 + kg * 8);
    }
  }

  // ---- per-thread gate elements: 2 consecutive hidden cols of one row
  const int er = tid >> 4;                       // 0..15 row within group
  const int ec = (tid & 15) * 2;                 // 0..30 col within block (even)
  const int grow = row0 + er;                    // global batch row
  const int guu = u0 + ec;                       // global hidden col

  float bs0[4], bs1[4];
#pragma unroll
  for (int gt = 0; gt < 4; ++gt) {
    bs0[gt] = bias[gt * UU + guu];
    bs1[gt] = bias[gt * UU + guu + 1];
  }

  float cv0 = init_cs[(size_t)grow * UU + guu];
  float cv1 = init_cs[(size_t)grow * UU + guu + 1];
  float hv0 = init_cs[(size_t)BB * UU + grow * UU + guu];
  float hv1 = init_cs[(size_t)BB * UU + grow * UU + guu + 1];

  const unsigned wswz = ((unsigned)(er & 7)) << 4;
  auto hstore = [&](int buf, float ha, float hb) {
    unsigned byteoff = (unsigned)er * 2048u + ((((unsigned)guu) * 2u) ^ wswz);
    char* base = (char*)hglob + ((size_t)(buf * 8 + g)) * 32768 + byteoff;
    us2 v; v[0] = f2bf(ha); v[1] = f2bf(hb);
    *(us2*)base = v;
  };

  {
    int m0 = masks[t0 * BB + grow];
    float s = m0 ? 0.f : 1.f;
    hstore(0, hv0 * s, hv1 * s);
  }

  unsigned target = 32;
  __syncthreads();
  if (tid == 0) {
    __threadfence();
    __hip_atomic_fetch_add(ctr, 1u, __ATOMIC_ACQ_REL, __HIP_MEMORY_SCOPE_AGENT);
    while (__hip_atomic_load(ctr, __ATOMIC_ACQUIRE, __HIP_MEMORY_SCOPE_AGENT) < target)
      __builtin_amdgcn_s_sleep(1);
    __threadfence();
  }
  __syncthreads();
  target += 32;

  // swizzled A-frag base pointers (row = l15, XOR bank swizzle on bits 4-6)
  const unsigned rswz = ((unsigned)(l15 & 7)) << 4;
  const char* hp0 = (const char*)hlds + l15 * 2048 + (((unsigned)(kg * 16 + 0)) ^ rswz);
  const char* hp1 = (const char*)hlds + l15 * 2048 + (((unsigned)(kg * 16 + 64)) ^ rswz);

  for (int tl = 0; tl < CHUNK; ++tl) {
    const int t = t0 + tl;
    // prefetch xz (4 x bf16x2) early; consumed after GEMM
    unsigned xzv[4];
    const size_t xrow = ((size_t)(tl * BB + grow)) * NZ;
#pragma unroll
    for (int gt = 0; gt < 4; ++gt)
      xzv[gt] = *(const unsigned*)(xz + xrow + gt * UU + guu);
    const int mcur = masks[t * BB + grow];
    const int mnext = (tl + 1 < CHUNK) ? masks[(t + 1) * BB + grow] : 0;

    // stage h (linear 32KB copy: global swizzled -> LDS swizzled)
    {
      const char* gsrc = (const char*)hglob + ((size_t)((tl & 1) * 8 + g)) * 32768;
      us8 sv[8];
#pragma unroll
      for (int i = 0; i < 8; ++i)
        sv[i] = *(const us8*)(gsrc + (i * 256 + tid) * 16);
#pragma unroll
      for (int i = 0; i < 8; ++i)
        *(us8*)((char*)hlds + (i * 256 + tid) * 16) = sv[i];
    }
    __syncthreads();

    // z = h @ Wh for this wave's gate (32 z-cols), rows = 16 batch rows
    f32x4 acc0 = {0.f, 0.f, 0.f, 0.f};
    f32x4 acc1 = {0.f, 0.f, 0.f, 0.f};
#pragma unroll
    for (int ks = 0; ks < 32; ++ks) {
      const char* p = ((ks & 1) ? hp1 : hp0) + (ks >> 1) * 128;
      bf16x8 a = *(const bf16x8*)p;
      acc0 = __builtin_amdgcn_mfma_f32_16x16x32_bf16(a, w0[ks], acc0, 0, 0, 0);
      acc1 = __builtin_amdgcn_mfma_f32_16x16x32_bf16(a, w1[ks], acc1, 0, 0, 0);
    }

    // exchange gates across waves via LDS
#pragma unroll
    for (int j = 0; j < 4; ++j) {
      zlds[wave][kg * 4 + j][l15] = acc0[j];
      zlds[wave][kg * 4 + j][16 + l15] = acc1[j];
    }
    __syncthreads();

    float z0[4], z1[4];
#pragma unroll
    for (int gt = 0; gt < 4; ++gt) {
      z0[gt] = zlds[gt][er][ec]     + bs0[gt] + bf2f((unsigned short)(xzv[gt] & 0xffffu));
      z1[gt] = zlds[gt][er][ec + 1] + bs1[gt] + bf2f((unsigned short)(xzv[gt] >> 16));
    }
    const float sm = mcur ? 0.f : 1.f;
    cv0 *= sm; cv1 *= sm;
    {
      float ig = sigm(z0[0]), fg = sigm(z0[1]), og = sigm(z0[2]), ug = tanh_(z0[3]);
      cv0 = fg * cv0 + ig * ug;
      hv0 = og * tanh_(cv0);
    }
    {
      float ig = sigm(z1[0]), fg = sigm(z1[1]), og = sigm(z1[2]), ug = tanh_(z1[3]);
      cv1 = fg * cv1 + ig * ug;
      hv1 = og * tanh_(cv1);
    }

    *(f32x2*)(out + (size_t)t * (BB * UU) + (size_t)grow * UU + guu) = (f32x2){hv0, hv1};

    if (tl + 1 < CHUNK) {
      const float sn = mnext ? 0.f : 1.f;
      hstore((tl + 1) & 1, hv0 * sn, hv1 * sn);
    }

    // group barrier (32 blocks)
    __syncthreads();
    if (tid == 0) {
      __threadfence();
      __hip_atomic_fetch_add(ctr, 1u, __ATOMIC_ACQ_REL, __HIP_MEMORY_SCOPE_AGENT);
      while (__hip_atomic_load(ctr, __ATOMIC_ACQUIRE, __HIP_MEMORY_SCOPE_AGENT) < target)
        __builtin_amdgcn_s_sleep(1);
      __threadfence();
    }
    __syncthreads();
    target += 32;
  }

  // chunk handoff state (f32), and final states into out tail on last chunk
  *(f32x2*)(fin_cs + (size_t)grow * UU + guu) = (f32x2){cv0, cv1};
  *(f32x2*)(fin_cs + (size_t)BB * UU + grow * UU + guu) = (f32x2){hv0, hv1};
  if (t0 == TT - CHUNK) {
    float* so = out + (size_t)TT * BB * UU;
    *(f32x2*)(so + (size_t)grow * UU + guu) = (f32x2){cv0, cv1};
    *(f32x2*)(so + (size_t)BB * UU + grow * UU + guu) = (f32x2){hv0, hv1};
  }
}

// ---------------------------------------------------------------------------
extern "C" void kernel_launch(void* const* d_in, const int* in_sizes, int n_in,
                              void* d_out, int out_size, void* d_ws, size_t ws_size,
                              hipStream_t stream) {
  const float* inputs  = (const float*)d_in[0];  // [256][128][1024]
  const float* states  = (const float*)d_in[1];  // [2][128][1024]
  const int*   masks   = (const int*)d_in[2];    // [256][128]
  const float* kernelx = (const float*)d_in[3];  // [1024][4096]
  const float* kernelh = (const float*)d_in[4];  // [1024][4096]
  const float* bias    = (const float*)d_in[5];  // [4096]
  float* out = (float*)d_out;
  char* ws = (char*)d_ws;

  // workspace layout (total 34MB)
  unsigned* bctr        = (unsigned*)ws;                                 // 1KB
  unsigned short* hglob = (unsigned short*)(ws + 65536);                 // 512KB
  float* state_ws       = (float*)(ws + 655360);                         // 1MB
  unsigned short* WhT   = (unsigned short*)(ws + (size_t)2  * 1048576);  // 8MB
  unsigned short* WxT   = (unsigned short*)(ws + (size_t)10 * 1048576);  // 8MB
  unsigned short* xzbuf = (unsigned short*)(ws + (size_t)18 * 1048576);  // 16MB

  // beacon: distinguish "k_scan never ran" (777s) from "nothing ran" (zeros)
  k_fill<<<dim3(2048), dim3(256), 0, stream>>>(out, out_size);

  k_transpose<<<dim3(64, 16), dim3(256), 0, stream>>>(kernelx, WxT);
  k_transpose<<<dim3(64, 16), dim3(256), 0, stream>>>(kernelh, WhT);

  for (int c = 0; c < NCHUNK; ++c) {
    const int t0 = c * CHUNK;
    k_gemm_xz<<<dim3(512), dim3(256), 0, stream>>>(inputs + (size_t)t0 * BB * DD, WxT, xzbuf);
    hipMemsetAsync(bctr, 0, 1024, stream);
    const float* init_cs = (c == 0) ? states : (const float*)state_ws;
    k_scan<<<dim3(256), dim3(256), 0, stream>>>(init_cs, masks, WhT, bias, xzbuf,
                                                out, state_ws, hglob, bctr, t0);
  }
}

// Round 4
// 1522.248 us; speedup vs baseline: 4.0256x; 4.0256x over previous
//
#include <hip/hip_runtime.h>

// ---------------------------------------------------------------------------
// LSTM: out[t] = h_t for t in [0,256);  final (c,h) appended.
//   T=256, B=128, D=1024, U=1024, 4U=4096
// Chunked pipeline (16 x 16 steps), single-stream serialized, ws = 34MB:
//   k_transpose : kernelx/kernelh f32 [1024][4096] -> W^T bf16 [4096][1024]
//   k_gemm_xz   : xz_chunk = inputs[t0..t0+16] @ kernelx  (bf16 MFMA)
//   k_scan      : plain launch, 256 blocks = 256 CUs, 1 block/CU;
//                 8 groups x 32 blocks, group g = blk&7 (XCD-aligned).
//                 Block owns 16 batch rows x 32 hidden cols; Wh slice PINNED
//                 in VGPRs (asm "+v"); h exchanged via swizzled global buf
//                 (same-XCD L2) with RELAXED atomic barrier + sc0 loads —
//                 no agent-scope fences (no L2 writeback/invalidate).
// ---------------------------------------------------------------------------

typedef float  f32x4 __attribute__((ext_vector_type(4)));
typedef float  f32x2 __attribute__((ext_vector_type(2)));
typedef __bf16 bf16x8 __attribute__((ext_vector_type(8)));
typedef unsigned short us8 __attribute__((ext_vector_type(8)));
typedef unsigned short us2 __attribute__((ext_vector_type(2)));
typedef unsigned int   u32x4 __attribute__((ext_vector_type(4)));

#define TT 256
#define BB 128
#define DD 1024
#define UU 1024
#define NZ 4096
#define CHUNK 16
#define NCHUNK 16

__device__ __forceinline__ unsigned short f2bf(float x) {
  union { float f; unsigned u; } v; v.f = x;
  unsigned r = v.u + 0x7fffu + ((v.u >> 16) & 1u);   // RNE
  return (unsigned short)(r >> 16);
}
__device__ __forceinline__ float bf2f(unsigned short b) {
  union { unsigned u; float f; } v; v.u = ((unsigned)b) << 16;
  return v.f;
}
__device__ __forceinline__ float sigm(float x) { return 1.f / (1.f + __expf(-x)); }
__device__ __forceinline__ float tanh_(float x) { return 1.f - 2.f / (__expf(2.f * x) + 1.f); }

// ---------------- transpose+convert: in f32 [1024][4096] -> out bf16 [4096][1024]
__global__ __launch_bounds__(256) void k_transpose(const float* __restrict__ in,
                                                   unsigned short* __restrict__ out) {
  __shared__ unsigned short tile[64][72];
  const int ni = blockIdx.x;           // 64 tiles along N=4096
  const int ki = blockIdx.y;           // 16 tiles along K=1024
  const int t = threadIdx.x;
  const int c = t & 63, r0 = t >> 6;
#pragma unroll
  for (int rr = 0; rr < 16; ++rr) {
    int r = r0 * 16 + rr;              // k-row within tile
    tile[r][c] = f2bf(in[(size_t)(ki * 64 + r) * NZ + ni * 64 + c]);
  }
  __syncthreads();
  const int kcol = t & 63, ng = t >> 6;
#pragma unroll
  for (int cc = 0; cc < 16; ++cc) {
    int n_off = ng * 16 + cc;
    out[(size_t)(ni * 64 + n_off) * DD + ki * 64 + kcol] = tile[kcol][n_off];
  }
}

// ---------------- phase 1 (per chunk): xz[2048][4096] bf16 = A[2048][1024] @ kernelx
// A f32 row-major, Bt = WxT bf16 [4096][1024] (k contiguous). 128x128 tile, BK=64.
__global__ __launch_bounds__(256, 2) void k_gemm_xz(const float* __restrict__ A,
                                                    const unsigned short* __restrict__ Bt,
                                                    unsigned short* __restrict__ C) {
  __shared__ unsigned short Al[2][128][72];
  __shared__ unsigned short Bl[2][128][72];
  const int bx = blockIdx.x;
  const int tn = bx & 31, tm = bx >> 5;          // 32 n-tiles, 16 m-tiles
  const int tid = threadIdx.x;
  const int wave = tid >> 6, lane = tid & 63;
  const int wr = wave >> 1, wc = wave & 1;
  const int l15 = lane & 15, kg = lane >> 4;

  f32x4 acc[4][4] = {};
  float4 ra[4][2];
  us8 rb[4];

  auto load_tile = [&](int kt) {
#pragma unroll
    for (int q = 0; q < 4; ++q) {
      int eidx = (q * 256 + tid) * 8;
      int row = eidx >> 6, col = eidx & 63;
      const float* p = A + (size_t)(tm * 128 + row) * DD + kt * 64 + col;
      ra[q][0] = *(const float4*)p;
      ra[q][1] = *(const float4*)(p + 4);
      rb[q] = *(const us8*)(Bt + (size_t)(tn * 128 + row) * DD + kt * 64 + col);
    }
  };
  auto store_tile = [&](int buf) {
#pragma unroll
    for (int q = 0; q < 4; ++q) {
      int eidx = (q * 256 + tid) * 8;
      int row = eidx >> 6, col = eidx & 63;
      us8 v;
      v[0] = f2bf(ra[q][0].x); v[1] = f2bf(ra[q][0].y);
      v[2] = f2bf(ra[q][0].z); v[3] = f2bf(ra[q][0].w);
      v[4] = f2bf(ra[q][1].x); v[5] = f2bf(ra[q][1].y);
      v[6] = f2bf(ra[q][1].z); v[7] = f2bf(ra[q][1].w);
      *(us8*)&Al[buf][row][col] = v;
      *(us8*)&Bl[buf][row][col] = rb[q];
    }
  };

  load_tile(0);
  store_tile(0);
  __syncthreads();

  for (int kt = 0; kt < 16; ++kt) {
    const int buf = kt & 1;
    if (kt < 15) load_tile(kt + 1);
#pragma unroll
    for (int ks = 0; ks < 2; ++ks) {
      bf16x8 af[4], bfr[4];
#pragma unroll
      for (int mi = 0; mi < 4; ++mi)
        af[mi] = *(const bf16x8*)&Al[buf][wr * 64 + mi * 16 + l15][ks * 32 + kg * 8];
#pragma unroll
      for (int ni = 0; ni < 4; ++ni)
        bfr[ni] = *(const bf16x8*)&Bl[buf][wc * 64 + ni * 16 + l15][ks * 32 + kg * 8];
#pragma unroll
      for (int mi = 0; mi < 4; ++mi)
#pragma unroll
        for (int ni = 0; ni < 4; ++ni)
          acc[mi][ni] = __builtin_amdgcn_mfma_f32_16x16x32_bf16(af[mi], bfr[ni], acc[mi][ni], 0, 0, 0);
    }
    if (kt < 15) store_tile(buf ^ 1);
    __syncthreads();
  }

#pragma unroll
  for (int ni = 0; ni < 4; ++ni) {
    const size_t col = (size_t)tn * 128 + wc * 64 + ni * 16 + l15;
#pragma unroll
    for (int mi = 0; mi < 4; ++mi) {
#pragma unroll
      for (int j = 0; j < 4; ++j) {
        const size_t row = (size_t)tm * 128 + wr * 64 + mi * 16 + kg * 4 + j;
        C[row * NZ + col] = f2bf(acc[mi][ni][j]);
      }
    }
  }
}

// ---------------- phase 2: scan over one 16-step chunk (plain launch)
// 256 blocks x 256 threads, 1 block/CU. group g = blk&7 (XCD-local), sb = blk>>3.
// Block owns batch rows [g*16, g*16+16) and hidden cols [sb*32, sb*32+32).
// wave = gate (i,f,o,u); Wh B-frags pinned in VGPRs via opaque asm.
__global__ __launch_bounds__(256, 1) void k_scan(const float* __restrict__ init_cs,
                                                 const int* __restrict__ masks,
                                                 const unsigned short* __restrict__ WhT,
                                                 const float* __restrict__ bias,
                                                 const unsigned short* __restrict__ xz,
                                                 float* __restrict__ out,
                                                 float* __restrict__ fin_cs,
                                                 unsigned short* __restrict__ hglob,
                                                 unsigned* __restrict__ bctr,
                                                 int t0) {
  __shared__ unsigned short hlds[16 * 1024];     // 32KB, swizzled layout
  __shared__ float zlds[4][16][33];

  const int tid = threadIdx.x;
  const int wave = tid >> 6, lane = tid & 63;
  const int l15 = lane & 15, kg = lane >> 4;
  const int blk = blockIdx.x;
  const int g = blk & 7;
  const int sb = blk >> 3;
  const int u0 = sb * 32;
  const int row0 = g * 16;
  unsigned* ctr = bctr + g * 32;                 // 128B apart per group

  // ---- Wh fragments resident in registers, PINNED (opaque to rematerializer)
  u32x4 w0[32], w1[32];
  {
    const size_t r0 = (size_t)(wave * UU + u0 + l15) * DD;
    const size_t r1 = (size_t)(wave * UU + u0 + 16 + l15) * DD;
#pragma unroll
    for (int ks = 0; ks < 32; ++ks) {
      w0[ks] = *(const u32x4*)(WhT + r0 + ks * 32 + kg * 8);
      w1[ks] = *(const u32x4*)(WhT + r1 + ks * 32 + kg * 8);
    }
#pragma unroll
    for (int ks = 0; ks < 32; ++ks) {
      asm volatile("" : "+v"(w0[ks]));
      asm volatile("" : "+v"(w1[ks]));
    }
  }

  // ---- per-thread gate elements: 2 consecutive hidden cols of one row
  const int er = tid >> 4;                       // 0..15 row within group
  const int ec = (tid & 15) * 2;                 // 0..30 col within block (even)
  const int grow = row0 + er;                    // global batch row
  const int guu = u0 + ec;                       // global hidden col

  float bs0[4], bs1[4];
#pragma unroll
  for (int gt = 0; gt < 4; ++gt) {
    bs0[gt] = bias[gt * UU + guu];
    bs1[gt] = bias[gt * UU + guu + 1];
  }

  float cv0 = init_cs[(size_t)grow * UU + guu];
  float cv1 = init_cs[(size_t)grow * UU + guu + 1];
  float hv0 = init_cs[(size_t)BB * UU + grow * UU + guu];
  float hv1 = init_cs[(size_t)BB * UU + grow * UU + guu + 1];

  const unsigned wswz = ((unsigned)(er & 7)) << 4;
  auto hstore = [&](int buf, float ha, float hb) {
    unsigned byteoff = (unsigned)er * 2048u + ((((unsigned)guu) * 2u) ^ wswz);
    char* base = (char*)hglob + ((size_t)(buf * 8 + g)) * 32768 + byteoff;
    us2 v; v[0] = f2bf(ha); v[1] = f2bf(hb);
    *(us2*)base = v;
  };

  {
    int m0 = masks[t0 * BB + grow];
    float s = m0 ? 0.f : 1.f;
    hstore(0, hv0 * s, hv1 * s);
  }

  // group barrier: XCD-local (g == XCD for round-robin block placement).
  // __syncthreads drains vmcnt(0) (stores acked at L2); relaxed atomics
  // execute at L2 with no cache maintenance; readers bypass L1 via sc0.
  unsigned target = 32;
  __syncthreads();
  if (tid == 0) {
    __hip_atomic_fetch_add(ctr, 1u, __ATOMIC_RELAXED, __HIP_MEMORY_SCOPE_AGENT);
    while (__hip_atomic_load(ctr, __ATOMIC_RELAXED, __HIP_MEMORY_SCOPE_AGENT) < target)
      __builtin_amdgcn_s_sleep(1);
  }
  __syncthreads();
  target += 32;

  // swizzled A-frag base pointers (row = l15, XOR bank swizzle on bits 4-6)
  const unsigned rswz = ((unsigned)(l15 & 7)) << 4;
  const char* hp0 = (const char*)hlds + l15 * 2048 + (((unsigned)(kg * 16 + 0)) ^ rswz);
  const char* hp1 = (const char*)hlds + l15 * 2048 + (((unsigned)(kg * 16 + 64)) ^ rswz);

  for (int tl = 0; tl < CHUNK; ++tl) {
    const int t = t0 + tl;

    // stage h: global (swizzled, same-XCD L2) -> regs via sc0 loads -> LDS
    u32x4 sv[8];
    {
      const char* gsrc = (const char*)hglob + ((size_t)((tl & 1) * 8 + g)) * 32768;
#pragma unroll
      for (int i = 0; i < 8; ++i) {
        const char* ap = gsrc + (i * 256 + tid) * 16;
        asm volatile("global_load_dwordx4 %0, %1, off sc0" : "=v"(sv[i]) : "v"(ap));
      }
    }
    // xz prefetch (4 x bf16x2); consumed after GEMM
    unsigned xzv[4];
    const size_t xrow = ((size_t)(tl * BB + grow)) * NZ;
#pragma unroll
    for (int gt = 0; gt < 4; ++gt)
      xzv[gt] = *(const unsigned*)(xz + xrow + gt * UU + guu);
    const int mcur = masks[t * BB + grow];
    const int mnext = (tl + 1 < CHUNK) ? masks[(t + 1) * BB + grow] : 0;

    asm volatile("s_waitcnt vmcnt(0)" ::: "memory");
    __builtin_amdgcn_sched_barrier(0);
#pragma unroll
    for (int i = 0; i < 8; ++i)
      *(u32x4*)((char*)hlds + (i * 256 + tid) * 16) = sv[i];
    __syncthreads();

    // z = h @ Wh for this wave's gate (32 z-cols), rows = 16 batch rows
    f32x4 acc0 = {0.f, 0.f, 0.f, 0.f};
    f32x4 acc1 = {0.f, 0.f, 0.f, 0.f};
#pragma unroll
    for (int ks = 0; ks < 32; ++ks) {
      const char* p = ((ks & 1) ? hp1 : hp0) + (ks >> 1) * 128;
      bf16x8 a = *(const bf16x8*)p;
      acc0 = __builtin_amdgcn_mfma_f32_16x16x32_bf16(a, __builtin_bit_cast(bf16x8, w0[ks]), acc0, 0, 0, 0);
      acc1 = __builtin_amdgcn_mfma_f32_16x16x32_bf16(a, __builtin_bit_cast(bf16x8, w1[ks]), acc1, 0, 0, 0);
    }

    // exchange gates across waves via LDS
#pragma unroll
    for (int j = 0; j < 4; ++j) {
      zlds[wave][kg * 4 + j][l15] = acc0[j];
      zlds[wave][kg * 4 + j][16 + l15] = acc1[j];
    }
    __syncthreads();

    float z0[4], z1[4];
#pragma unroll
    for (int gt = 0; gt < 4; ++gt) {
      z0[gt] = zlds[gt][er][ec]     + bs0[gt] + bf2f((unsigned short)(xzv[gt] & 0xffffu));
      z1[gt] = zlds[gt][er][ec + 1] + bs1[gt] + bf2f((unsigned short)(xzv[gt] >> 16));
    }
    const float sm = mcur ? 0.f : 1.f;
    cv0 *= sm; cv1 *= sm;
    {
      float ig = sigm(z0[0]), fg = sigm(z0[1]), og = sigm(z0[2]), ug = tanh_(z0[3]);
      cv0 = fg * cv0 + ig * ug;
      hv0 = og * tanh_(cv0);
    }
    {
      float ig = sigm(z1[0]), fg = sigm(z1[1]), og = sigm(z1[2]), ug = tanh_(z1[3]);
      cv1 = fg * cv1 + ig * ug;
      hv1 = og * tanh_(cv1);
    }

    *(f32x2*)(out + (size_t)t * (BB * UU) + (size_t)grow * UU + guu) = (f32x2){hv0, hv1};

    if (tl + 1 < CHUNK) {
      const float sn = mnext ? 0.f : 1.f;
      hstore((tl + 1) & 1, hv0 * sn, hv1 * sn);
    }

    // group barrier (32 blocks, XCD-local, relaxed)
    __syncthreads();
    if (tid == 0) {
      __hip_atomic_fetch_add(ctr, 1u, __ATOMIC_RELAXED, __HIP_MEMORY_SCOPE_AGENT);
      while (__hip_atomic_load(ctr, __ATOMIC_RELAXED, __HIP_MEMORY_SCOPE_AGENT) < target)
        __builtin_amdgcn_s_sleep(1);
    }
    __syncthreads();
    target += 32;
  }

  // chunk handoff state (f32), and final states into out tail on last chunk
  *(f32x2*)(fin_cs + (size_t)grow * UU + guu) = (f32x2){cv0, cv1};
  *(f32x2*)(fin_cs + (size_t)BB * UU + grow * UU + guu) = (f32x2){hv0, hv1};
  if (t0 == TT - CHUNK) {
    float* so = out + (size_t)TT * BB * UU;
    *(f32x2*)(so + (size_t)grow * UU + guu) = (f32x2){cv0, cv1};
    *(f32x2*)(so + (size_t)BB * UU + grow * UU + guu) = (f32x2){hv0, hv1};
  }
}

// ---------------------------------------------------------------------------
extern "C" void kernel_launch(void* const* d_in, const int* in_sizes, int n_in,
                              void* d_out, int out_size, void* d_ws, size_t ws_size,
                              hipStream_t stream) {
  const float* inputs  = (const float*)d_in[0];  // [256][128][1024]
  const float* states  = (const float*)d_in[1];  // [2][128][1024]
  const int*   masks   = (const int*)d_in[2];    // [256][128]
  const float* kernelx = (const float*)d_in[3];  // [1024][4096]
  const float* kernelh = (const float*)d_in[4];  // [1024][4096]
  const float* bias    = (const float*)d_in[5];  // [4096]
  float* out = (float*)d_out;
  char* ws = (char*)d_ws;

  // workspace layout (total 34MB)
  unsigned* bctr        = (unsigned*)ws;                                 // 1KB
  unsigned short* hglob = (unsigned short*)(ws + 65536);                 // 512KB
  float* state_ws       = (float*)(ws + 655360);                         // 1MB
  unsigned short* WhT   = (unsigned short*)(ws + (size_t)2  * 1048576);  // 8MB
  unsigned short* WxT   = (unsigned short*)(ws + (size_t)10 * 1048576);  // 8MB
  unsigned short* xzbuf = (unsigned short*)(ws + (size_t)18 * 1048576);  // 16MB

  k_transpose<<<dim3(64, 16), dim3(256), 0, stream>>>(kernelx, WxT);
  k_transpose<<<dim3(64, 16), dim3(256), 0, stream>>>(kernelh, WhT);

  for (int c = 0; c < NCHUNK; ++c) {
    const int t0 = c * CHUNK;
    k_gemm_xz<<<dim3(512), dim3(256), 0, stream>>>(inputs + (size_t)t0 * BB * DD, WxT, xzbuf);
    hipMemsetAsync(bctr, 0, 1024, stream);
    const float* init_cs = (c == 0) ? states : (const float*)state_ws;
    k_scan<<<dim3(256), dim3(256), 0, stream>>>(init_cs, masks, WhT, bias, xzbuf,
                                                out, state_ws, hglob, bctr, t0);
  }
}

// Round 5
// 1479.359 us; speedup vs baseline: 4.1423x; 1.0290x over previous
//
#include <hip/hip_runtime.h>

// ---------------------------------------------------------------------------
// LSTM: out[t] = h_t for t in [0,256);  final (c,h) appended.
//   T=256, B=128, D=1024, U=1024, 4U=4096
// Full pipeline (ws >= 338MB; else fall back to chunked round-4 path):
//   k_convert   : inputs f32 -> bf16 (one pass)
//   k_transpose : kernelx/kernelh f32 [1024][4096] -> W^T bf16 [4096][1024]
//   k_gemm_bf   : xz = inputs_bf @ kernelx, single launch, m97 structure
//                 (128x128 tile, BK=64, dbuf global_load_lds w16, XCD swizzle)
//   k_scan      : single launch, 256 steps; 256 blocks = 256 CUs, 1 block/CU;
//                 8 groups x 32 blocks (g = blk&7, XCD-local); block owns
//                 16 batch rows x 32 hidden cols; Wh pinned in VGPRs;
//                 h exchanged via swizzled global buf (same-XCD L2) with
//                 relaxed atomic barrier + sc0 loads.
// ---------------------------------------------------------------------------

typedef float  f32x4 __attribute__((ext_vector_type(4)));
typedef float  f32x2 __attribute__((ext_vector_type(2)));
typedef __bf16 bf16x8 __attribute__((ext_vector_type(8)));
typedef unsigned short us8 __attribute__((ext_vector_type(8)));
typedef unsigned short us2 __attribute__((ext_vector_type(2)));
typedef unsigned int   u32x4 __attribute__((ext_vector_type(4)));

#define TT 256
#define BB 128
#define DD 1024
#define UU 1024
#define NZ 4096
#define CHUNK 16
#define NCHUNK 16

typedef __attribute__((address_space(3))) unsigned       lds_u32;
typedef const __attribute__((address_space(1))) unsigned glob_u32;
__device__ __forceinline__ void gll16(glob_u32* g, lds_u32* l) {
  __builtin_amdgcn_global_load_lds(g, l, 16, 0, 0);
}

__device__ __forceinline__ unsigned short f2bf(float x) {
  union { float f; unsigned u; } v; v.f = x;
  unsigned r = v.u + 0x7fffu + ((v.u >> 16) & 1u);   // RNE
  return (unsigned short)(r >> 16);
}
__device__ __forceinline__ float bf2f(unsigned short b) {
  union { unsigned u; float f; } v; v.u = ((unsigned)b) << 16;
  return v.f;
}
__device__ __forceinline__ float sigm(float x) { return 1.f / (1.f + __expf(-x)); }
__device__ __forceinline__ float tanh_(float x) { return 1.f - 2.f / (__expf(2.f * x) + 1.f); }

// ---------------- f32 -> bf16 bulk convert (8 elems/thread)
__global__ __launch_bounds__(256) void k_convert(const float* __restrict__ in,
                                                 unsigned short* __restrict__ out,
                                                 int n8) {
  int i = blockIdx.x * 256 + threadIdx.x;
  if (i >= n8) return;
  const float4 a = *(const float4*)(in + (size_t)i * 8);
  const float4 b = *(const float4*)(in + (size_t)i * 8 + 4);
  us8 v;
  v[0] = f2bf(a.x); v[1] = f2bf(a.y); v[2] = f2bf(a.z); v[3] = f2bf(a.w);
  v[4] = f2bf(b.x); v[5] = f2bf(b.y); v[6] = f2bf(b.z); v[7] = f2bf(b.w);
  *(us8*)(out + (size_t)i * 8) = v;
}

// ---------------- transpose+convert: in f32 [1024][4096] -> out bf16 [4096][1024]
__global__ __launch_bounds__(256) void k_transpose(const float* __restrict__ in,
                                                   unsigned short* __restrict__ out) {
  __shared__ unsigned short tile[64][72];
  const int ni = blockIdx.x;           // 64 tiles along N=4096
  const int ki = blockIdx.y;           // 16 tiles along K=1024
  const int t = threadIdx.x;
  const int c = t & 63, r0 = t >> 6;
#pragma unroll
  for (int rr = 0; rr < 16; ++rr) {
    int r = r0 * 16 + rr;              // k-row within tile
    tile[r][c] = f2bf(in[(size_t)(ki * 64 + r) * NZ + ni * 64 + c]);
  }
  __syncthreads();
  const int kcol = t & 63, ng = t >> 6;
#pragma unroll
  for (int cc = 0; cc < 16; ++cc) {
    int n_off = ng * 16 + cc;
    out[(size_t)(ni * 64 + n_off) * DD + ki * 64 + kcol] = tile[kcol][n_off];
  }
}

// ---------------- xz = A_bf16[32768][1024] @ WxT^T, m97 structure, single launch
// grid 8192 = 256 m-tiles x 32 n-tiles, bijective XCD swizzle (8192 % 8 == 0).
__global__ __launch_bounds__(256, 2) void k_gemm_bf(const unsigned short* __restrict__ A,
                                                    const unsigned short* __restrict__ Bt,
                                                    unsigned short* __restrict__ C) {
  __shared__ unsigned short Al[2][128 * 64];
  __shared__ unsigned short Bl[2][128 * 64];
  const int bx = blockIdx.x;
  const int wgid = (bx & 7) * 1024 + (bx >> 3);  // XCD-contiguous chunks
  const int tm = wgid >> 5, tn = wgid & 31;
  const int tid = threadIdx.x;
  const int wave = tid >> 6, lane = tid & 63;
  const int wr = wave >> 1, wc = wave & 1;
  const int l15 = lane & 15, kg = lane >> 4;

  f32x4 acc[4][4] = {};

  const int srow = tid >> 3;                     // 0..31 row per issue
  const int scol = (tid & 7) * 8;                // element col within BK=64
  const unsigned sdst = tid * 8;                 // LDS element offset (linear)

  auto stage = [&](int buf, int kt) {
#pragma unroll
    for (int i = 0; i < 4; ++i) {
      gll16((glob_u32*)(A  + (size_t)(tm * 128 + i * 32 + srow) * DD + kt * 64 + scol),
            (lds_u32*)&Al[buf][i * 2048 + sdst]);
      gll16((glob_u32*)(Bt + (size_t)(tn * 128 + i * 32 + srow) * DD + kt * 64 + scol),
            (lds_u32*)&Bl[buf][i * 2048 + sdst]);
    }
  };

  stage(0, 0);
  __syncthreads();

  for (int kt = 0; kt < 16; ++kt) {
    const int buf = kt & 1;
    if (kt < 15) stage(buf ^ 1, kt + 1);
#pragma unroll
    for (int ks = 0; ks < 2; ++ks) {
      bf16x8 af[4], bfr[4];
#pragma unroll
      for (int mi = 0; mi < 4; ++mi)
        af[mi] = *(const bf16x8*)&Al[buf][(wr * 64 + mi * 16 + l15) * 64 + ks * 32 + kg * 8];
#pragma unroll
      for (int ni = 0; ni < 4; ++ni)
        bfr[ni] = *(const bf16x8*)&Bl[buf][(wc * 64 + ni * 16 + l15) * 64 + ks * 32 + kg * 8];
#pragma unroll
      for (int mi = 0; mi < 4; ++mi)
#pragma unroll
        for (int ni = 0; ni < 4; ++ni)
          acc[mi][ni] = __builtin_amdgcn_mfma_f32_16x16x32_bf16(af[mi], bfr[ni], acc[mi][ni], 0, 0, 0);
    }
    __syncthreads();   // drains lgkm + vmcnt -> next buf staged & this buf free
  }

#pragma unroll
  for (int ni = 0; ni < 4; ++ni) {
    const size_t col = (size_t)tn * 128 + wc * 64 + ni * 16 + l15;
#pragma unroll
    for (int mi = 0; mi < 4; ++mi) {
#pragma unroll
      for (int j = 0; j < 4; ++j) {
        const size_t row = (size_t)tm * 128 + wr * 64 + mi * 16 + kg * 4 + j;
        C[row * NZ + col] = f2bf(acc[mi][ni][j]);
      }
    }
  }
}

// ---------------- fallback gemm (round-4 path, f32 A): xz_chunk = A[2048][1024] @ WxT^T
__global__ __launch_bounds__(256, 2) void k_gemm_fb(const float* __restrict__ A,
                                                    const unsigned short* __restrict__ Bt,
                                                    unsigned short* __restrict__ C) {
  __shared__ unsigned short Al[2][128][72];
  __shared__ unsigned short Bl[2][128][72];
  const int bx = blockIdx.x;
  const int tn = bx & 31, tm = bx >> 5;
  const int tid = threadIdx.x;
  const int wave = tid >> 6, lane = tid & 63;
  const int wr = wave >> 1, wc = wave & 1;
  const int l15 = lane & 15, kg = lane >> 4;

  f32x4 acc[4][4] = {};
  float4 ra[4][2];
  us8 rb[4];

  auto load_tile = [&](int kt) {
#pragma unroll
    for (int q = 0; q < 4; ++q) {
      int eidx = (q * 256 + tid) * 8;
      int row = eidx >> 6, col = eidx & 63;
      const float* p = A + (size_t)(tm * 128 + row) * DD + kt * 64 + col;
      ra[q][0] = *(const float4*)p;
      ra[q][1] = *(const float4*)(p + 4);
      rb[q] = *(const us8*)(Bt + (size_t)(tn * 128 + row) * DD + kt * 64 + col);
    }
  };
  auto store_tile = [&](int buf) {
#pragma unroll
    for (int q = 0; q < 4; ++q) {
      int eidx = (q * 256 + tid) * 8;
      int row = eidx >> 6, col = eidx & 63;
      us8 v;
      v[0] = f2bf(ra[q][0].x); v[1] = f2bf(ra[q][0].y);
      v[2] = f2bf(ra[q][0].z); v[3] = f2bf(ra[q][0].w);
      v[4] = f2bf(ra[q][1].x); v[5] = f2bf(ra[q][1].y);
      v[6] = f2bf(ra[q][1].z); v[7] = f2bf(ra[q][1].w);
      *(us8*)&Al[buf][row][col] = v;
      *(us8*)&Bl[buf][row][col] = rb[q];
    }
  };

  load_tile(0);
  store_tile(0);
  __syncthreads();

  for (int kt = 0; kt < 16; ++kt) {
    const int buf = kt & 1;
    if (kt < 15) load_tile(kt + 1);
#pragma unroll
    for (int ks = 0; ks < 2; ++ks) {
      bf16x8 af[4], bfr[4];
#pragma unroll
      for (int mi = 0; mi < 4; ++mi)
        af[mi] = *(const bf16x8*)&Al[buf][wr * 64 + mi * 16 + l15][ks * 32 + kg * 8];
#pragma unroll
      for (int ni = 0; ni < 4; ++ni)
        bfr[ni] = *(const bf16x8*)&Bl[buf][wc * 64 + ni * 16 + l15][ks * 32 + kg * 8];
#pragma unroll
      for (int mi = 0; mi < 4; ++mi)
#pragma unroll
        for (int ni = 0; ni < 4; ++ni)
          acc[mi][ni] = __builtin_amdgcn_mfma_f32_16x16x32_bf16(af[mi], bfr[ni], acc[mi][ni], 0, 0, 0);
    }
    if (kt < 15) store_tile(buf ^ 1);
    __syncthreads();
  }

#pragma unroll
  for (int ni = 0; ni < 4; ++ni) {
    const size_t col = (size_t)tn * 128 + wc * 64 + ni * 16 + l15;
#pragma unroll
    for (int mi = 0; mi < 4; ++mi) {
#pragma unroll
      for (int j = 0; j < 4; ++j) {
        const size_t row = (size_t)tm * 128 + wr * 64 + mi * 16 + kg * 4 + j;
        C[row * NZ + col] = f2bf(acc[mi][ni][j]);
      }
    }
  }
}

// ---------------- scan over nsteps (plain launch, 256 blocks x 256 thr, 1/CU)
__global__ __launch_bounds__(256, 1) void k_scan(const float* __restrict__ init_cs,
                                                 const int* __restrict__ masks,
                                                 const unsigned short* __restrict__ WhT,
                                                 const float* __restrict__ bias,
                                                 const unsigned short* __restrict__ xz,
                                                 float* __restrict__ out,
                                                 float* __restrict__ fin_cs,
                                                 unsigned short* __restrict__ hglob,
                                                 unsigned* __restrict__ bctr,
                                                 int t0, int nsteps) {
  __shared__ unsigned short hlds[16 * 1024];     // 32KB, swizzled layout
  __shared__ float zlds[4][16][33];

  const int tid = threadIdx.x;
  const int wave = tid >> 6, lane = tid & 63;
  const int l15 = lane & 15, kg = lane >> 4;
  const int blk = blockIdx.x;
  const int g = blk & 7;
  const int sb = blk >> 3;
  const int u0 = sb * 32;
  const int row0 = g * 16;
  unsigned* ctr = bctr + g * 32;                 // 128B apart per group

  // ---- Wh fragments resident in registers, PINNED (opaque to rematerializer)
  u32x4 w0[32], w1[32];
  {
    const size_t r0 = (size_t)(wave * UU + u0 + l15) * DD;
    const size_t r1 = (size_t)(wave * UU + u0 + 16 + l15) * DD;
#pragma unroll
    for (int ks = 0; ks < 32; ++ks) {
      w0[ks] = *(const u32x4*)(WhT + r0 + ks * 32 + kg * 8);
      w1[ks] = *(const u32x4*)(WhT + r1 + ks * 32 + kg * 8);
    }
#pragma unroll
    for (int ks = 0; ks < 32; ++ks) {
      asm volatile("" : "+v"(w0[ks]));
      asm volatile("" : "+v"(w1[ks]));
    }
  }

  // ---- per-thread gate elements: 2 consecutive hidden cols of one row
  const int er = tid >> 4;                       // 0..15 row within group
  const int ec = (tid & 15) * 2;                 // 0..30 col within block (even)
  const int grow = row0 + er;                    // global batch row
  const int guu = u0 + ec;                       // global hidden col

  float bs0[4], bs1[4];
#pragma unroll
  for (int gt = 0; gt < 4; ++gt) {
    bs0[gt] = bias[gt * UU + guu];
    bs1[gt] = bias[gt * UU + guu + 1];
  }

  float cv0 = init_cs[(size_t)grow * UU + guu];
  float cv1 = init_cs[(size_t)grow * UU + guu + 1];
  float hv0 = init_cs[(size_t)BB * UU + grow * UU + guu];
  float hv1 = init_cs[(size_t)BB * UU + grow * UU + guu + 1];

  const unsigned wswz = ((unsigned)(er & 7)) << 4;
  auto hstore = [&](int buf, float ha, float hb) {
    unsigned byteoff = (unsigned)er * 2048u + ((((unsigned)guu) * 2u) ^ wswz);
    char* base = (char*)hglob + ((size_t)(buf * 8 + g)) * 32768 + byteoff;
    us2 v; v[0] = f2bf(ha); v[1] = f2bf(hb);
    *(us2*)base = v;
  };

  {
    int m0 = masks[t0 * BB + grow];
    float s = m0 ? 0.f : 1.f;
    hstore(0, hv0 * s, hv1 * s);
  }

  // group barrier: XCD-local (g == XCD for round-robin block placement).
  unsigned target = 32;
  __syncthreads();
  if (tid == 0) {
    __hip_atomic_fetch_add(ctr, 1u, __ATOMIC_RELAXED, __HIP_MEMORY_SCOPE_AGENT);
    while (__hip_atomic_load(ctr, __ATOMIC_RELAXED, __HIP_MEMORY_SCOPE_AGENT) < target)
      __builtin_amdgcn_s_sleep(1);
  }
  __syncthreads();
  target += 32;

  // swizzled A-frag base pointers (row = l15, XOR bank swizzle on bits 4-6)
  const unsigned rswz = ((unsigned)(l15 & 7)) << 4;
  const char* hp0 = (const char*)hlds + l15 * 2048 + (((unsigned)(kg * 16 + 0)) ^ rswz);
  const char* hp1 = (const char*)hlds + l15 * 2048 + (((unsigned)(kg * 16 + 64)) ^ rswz);

  for (int tl = 0; tl < nsteps; ++tl) {
    const int t = t0 + tl;

    // stage h: global (swizzled, same-XCD L2) -> regs via sc0 loads -> LDS
    u32x4 sv[8];
    {
      const char* gsrc = (const char*)hglob + ((size_t)((tl & 1) * 8 + g)) * 32768;
#pragma unroll
      for (int i = 0; i < 8; ++i) {
        const char* ap = gsrc + (i * 256 + tid) * 16;
        asm volatile("global_load_dwordx4 %0, %1, off sc0" : "=v"(sv[i]) : "v"(ap));
      }
    }
    // xz prefetch (4 x bf16x2); consumed after GEMM
    unsigned xzv[4];
    const size_t xrow = ((size_t)(tl * BB + grow)) * NZ;
#pragma unroll
    for (int gt = 0; gt < 4; ++gt)
      xzv[gt] = *(const unsigned*)(xz + xrow + gt * UU + guu);
    const int mcur = masks[t * BB + grow];
    const int mnext = (tl + 1 < nsteps) ? masks[(t + 1) * BB + grow] : 0;

    asm volatile("s_waitcnt vmcnt(0)" ::: "memory");
    __builtin_amdgcn_sched_barrier(0);
#pragma unroll
    for (int i = 0; i < 8; ++i)
      *(u32x4*)((char*)hlds + (i * 256 + tid) * 16) = sv[i];
    __syncthreads();

    // z = h @ Wh for this wave's gate (32 z-cols), rows = 16 batch rows
    f32x4 acc0 = {0.f, 0.f, 0.f, 0.f};
    f32x4 acc1 = {0.f, 0.f, 0.f, 0.f};
#pragma unroll
    for (int ks = 0; ks < 32; ++ks) {
      const char* p = ((ks & 1) ? hp1 : hp0) + (ks >> 1) * 128;
      bf16x8 a = *(const bf16x8*)p;
      acc0 = __builtin_amdgcn_mfma_f32_16x16x32_bf16(a, __builtin_bit_cast(bf16x8, w0[ks]), acc0, 0, 0, 0);
      acc1 = __builtin_amdgcn_mfma_f32_16x16x32_bf16(a, __builtin_bit_cast(bf16x8, w1[ks]), acc1, 0, 0, 0);
    }

    // exchange gates across waves via LDS
#pragma unroll
    for (int j = 0; j < 4; ++j) {
      zlds[wave][kg * 4 + j][l15] = acc0[j];
      zlds[wave][kg * 4 + j][16 + l15] = acc1[j];
    }
    __syncthreads();

    float z0[4], z1[4];
#pragma unroll
    for (int gt = 0; gt < 4; ++gt) {
      z0[gt] = zlds[gt][er][ec]     + bs0[gt] + bf2f((unsigned short)(xzv[gt] & 0xffffu));
      z1[gt] = zlds[gt][er][ec + 1] + bs1[gt] + bf2f((unsigned short)(xzv[gt] >> 16));
    }
    const float sm = mcur ? 0.f : 1.f;
    cv0 *= sm; cv1 *= sm;
    {
      float ig = sigm(z0[0]), fg = sigm(z0[1]), og = sigm(z0[2]), ug = tanh_(z0[3]);
      cv0 = fg * cv0 + ig * ug;
      hv0 = og * tanh_(cv0);
    }
    {
      float ig = sigm(z1[0]), fg = sigm(z1[1]), og = sigm(z1[2]), ug = tanh_(z1[3]);
      cv1 = fg * cv1 + ig * ug;
      hv1 = og * tanh_(cv1);
    }

    *(f32x2*)(out + (size_t)t * (BB * UU) + (size_t)grow * UU + guu) = (f32x2){hv0, hv1};

    if (tl + 1 < nsteps) {
      const float sn = mnext ? 0.f : 1.f;
      hstore((tl + 1) & 1, hv0 * sn, hv1 * sn);
    }

    // group barrier (32 blocks, XCD-local, relaxed)
    __syncthreads();
    if (tid == 0) {
      __hip_atomic_fetch_add(ctr, 1u, __ATOMIC_RELAXED, __HIP_MEMORY_SCOPE_AGENT);
      while (__hip_atomic_load(ctr, __ATOMIC_RELAXED, __HIP_MEMORY_SCOPE_AGENT) < target)
        __builtin_amdgcn_s_sleep(1);
    }
    __syncthreads();
    target += 32;
  }

  // chunk handoff state (f32), and final states into out tail on last chunk
  *(f32x2*)(fin_cs + (size_t)grow * UU + guu) = (f32x2){cv0, cv1};
  *(f32x2*)(fin_cs + (size_t)BB * UU + grow * UU + guu) = (f32x2){hv0, hv1};
  if (t0 + nsteps == TT) {
    float* so = out + (size_t)TT * BB * UU;
    *(f32x2*)(so + (size_t)grow * UU + guu) = (f32x2){cv0, cv1};
    *(f32x2*)(so + (size_t)BB * UU + grow * UU + guu) = (f32x2){hv0, hv1};
  }
}

// ---------------------------------------------------------------------------
extern "C" void kernel_launch(void* const* d_in, const int* in_sizes, int n_in,
                              void* d_out, int out_size, void* d_ws, size_t ws_size,
                              hipStream_t stream) {
  const float* inputs  = (const float*)d_in[0];  // [256][128][1024]
  const float* states  = (const float*)d_in[1];  // [2][128][1024]
  const int*   masks   = (const int*)d_in[2];    // [256][128]
  const float* kernelx = (const float*)d_in[3];  // [1024][4096]
  const float* kernelh = (const float*)d_in[4];  // [1024][4096]
  const float* bias    = (const float*)d_in[5];  // [4096]
  float* out = (float*)d_out;
  char* ws = (char*)d_ws;

  // common workspace head
  unsigned* bctr        = (unsigned*)ws;                                 // 1KB
  unsigned short* hglob = (unsigned short*)(ws + 65536);                 // 512KB
  float* state_ws       = (float*)(ws + 655360);                         // 1MB
  unsigned short* WhT   = (unsigned short*)(ws + (size_t)2  * 1048576);  // 8MB
  unsigned short* WxT   = (unsigned short*)(ws + (size_t)10 * 1048576);  // 8MB
  unsigned short* Abf   = (unsigned short*)(ws + (size_t)18 * 1048576);  // 64MB
  unsigned short* xzbig = (unsigned short*)(ws + (size_t)82 * 1048576);  // 256MB
  unsigned short* xzsml = (unsigned short*)(ws + (size_t)18 * 1048576);  // 16MB (fallback)

  const size_t WS_NEEDED = (size_t)338 * 1048576;

  k_transpose<<<dim3(64, 16), dim3(256), 0, stream>>>(kernelx, WxT);
  k_transpose<<<dim3(64, 16), dim3(256), 0, stream>>>(kernelh, WhT);

  if (ws_size >= WS_NEEDED) {
    // ---- full path: one convert, one GEMM, one scan
    k_convert<<<dim3(16384), dim3(256), 0, stream>>>(inputs, Abf, (TT * BB * DD) / 8);
    k_gemm_bf<<<dim3(8192), dim3(256), 0, stream>>>(Abf, WxT, xzbig);
    hipMemsetAsync(bctr, 0, 1024, stream);
    k_scan<<<dim3(256), dim3(256), 0, stream>>>(states, masks, WhT, bias, xzbig,
                                                out, state_ws, hglob, bctr, 0, TT);
  } else {
    // ---- fallback: round-4 chunked path
    for (int c = 0; c < NCHUNK; ++c) {
      const int t0 = c * CHUNK;
      k_gemm_fb<<<dim3(512), dim3(256), 0, stream>>>(inputs + (size_t)t0 * BB * DD, WxT, xzsml);
      hipMemsetAsync(bctr, 0, 1024, stream);
      const float* init_cs = (c == 0) ? states : (const float*)state_ws;
      k_scan<<<dim3(256), dim3(256), 0, stream>>>(init_cs, masks, WhT, bias, xzsml,
                                                  out, state_ws, hglob, bctr, t0, CHUNK);
    }
  }
}

// Round 7
// 1236.273 us; speedup vs baseline: 4.9568x; 1.1966x over previous
//
#include <hip/hip_runtime.h>

// ---------------------------------------------------------------------------
// LSTM: out[t] = h_t for t in [0,256);  final (c,h) appended.
//   T=256, B=128, D=1024, U=1024, 4U=4096
// Pipeline (ws ~338MB):
//   k_convert   : inputs f32 -> bf16
//   k_transpose : kernelx/kernelh f32 [1024][4096] -> W^T bf16 [4096][1024]
//   k_gemm_bf   : xz = inputs_bf @ kernelx (m97 structure; transposed-MFMA
//                 epilogue -> coalesced 8B C-stores)
//   k_scan      : single launch, 256 steps, 256 blocks = 256 CUs, 1/CU;
//                 8 groups x 32 blocks (g = blk&7, XCD-local).
//                 Round-5-proven staging (asm sc0 dwordx4 -> LDS -> sync).
//                 xz loads issued AFTER staging barrier (drain lands after
//                 MFMA phase). Distributed flag barrier: 1 plain store +
//                 64-lane parallel poll (replaces 32 serialized atomics).
// ---------------------------------------------------------------------------

typedef float  f32x4 __attribute__((ext_vector_type(4)));
typedef float  f32x2 __attribute__((ext_vector_type(2)));
typedef __bf16 bf16x8 __attribute__((ext_vector_type(8)));
typedef unsigned short us8 __attribute__((ext_vector_type(8)));
typedef unsigned short us4 __attribute__((ext_vector_type(4)));
typedef unsigned int   u32x4 __attribute__((ext_vector_type(4)));

#define TT 256
#define BB 128
#define DD 1024
#define UU 1024
#define NZ 4096

typedef __attribute__((address_space(3))) unsigned       lds_u32;
typedef const __attribute__((address_space(1))) unsigned glob_u32;

__device__ __forceinline__ unsigned short f2bf(float x) {
  union { float f; unsigned u; } v; v.f = x;
  unsigned r = v.u + 0x7fffu + ((v.u >> 16) & 1u);   // RNE
  return (unsigned short)(r >> 16);
}
__device__ __forceinline__ float bf2f(unsigned short b) {
  union { unsigned u; float f; } v; v.u = ((unsigned)b) << 16;
  return v.f;
}
__device__ __forceinline__ float sigm(float x) { return 1.f / (1.f + __expf(-x)); }
__device__ __forceinline__ float tanh_(float x) { return 1.f - 2.f / (__expf(2.f * x) + 1.f); }

// ---------------- f32 -> bf16 bulk convert (8 elems/thread)
__global__ __launch_bounds__(256) void k_convert(const float* __restrict__ in,
                                                 unsigned short* __restrict__ out,
                                                 int n8) {
  int i = blockIdx.x * 256 + threadIdx.x;
  if (i >= n8) return;
  const float4 a = *(const float4*)(in + (size_t)i * 8);
  const float4 b = *(const float4*)(in + (size_t)i * 8 + 4);
  us8 v;
  v[0] = f2bf(a.x); v[1] = f2bf(a.y); v[2] = f2bf(a.z); v[3] = f2bf(a.w);
  v[4] = f2bf(b.x); v[5] = f2bf(b.y); v[6] = f2bf(b.z); v[7] = f2bf(b.w);
  *(us8*)(out + (size_t)i * 8) = v;
}

// ---------------- transpose+convert: in f32 [1024][4096] -> out bf16 [4096][1024]
__global__ __launch_bounds__(256) void k_transpose(const float* __restrict__ in,
                                                   unsigned short* __restrict__ out) {
  __shared__ unsigned short tile[64][72];
  const int ni = blockIdx.x;
  const int ki = blockIdx.y;
  const int t = threadIdx.x;
  const int c = t & 63, r0 = t >> 6;
#pragma unroll
  for (int rr = 0; rr < 16; ++rr) {
    int r = r0 * 16 + rr;
    tile[r][c] = f2bf(in[(size_t)(ki * 64 + r) * NZ + ni * 64 + c]);
  }
  __syncthreads();
  const int kcol = t & 63, ng = t >> 6;
#pragma unroll
  for (int cc = 0; cc < 16; ++cc) {
    int n_off = ng * 16 + cc;
    out[(size_t)(ni * 64 + n_off) * DD + ki * 64 + kcol] = tile[kcol][n_off];
  }
}

// ---------------- xz = A_bf16[32768][1024] @ WxT^T, m97 structure, single launch
// grid 8192 = 256 m-tiles x 32 n-tiles, XCD swizzle. Transposed MFMA: acc[ni][mi]
// holds D with row=m via l15, col=n via kg*4+j -> 8B coalesced C-stores.
__global__ __launch_bounds__(256, 2) void k_gemm_bf(const unsigned short* __restrict__ A,
                                                    const unsigned short* __restrict__ Bt,
                                                    unsigned short* __restrict__ C) {
  __shared__ unsigned short Al[2][128 * 64];
  __shared__ unsigned short Bl[2][128 * 64];
  const int bx = blockIdx.x;
  const int wgid = (bx & 7) * 1024 + (bx >> 3);
  const int tm = wgid >> 5, tn = wgid & 31;
  const int tid = threadIdx.x;
  const int wave = tid >> 6, lane = tid & 63;
  const int wr = wave >> 1, wc = wave & 1;
  const int l15 = lane & 15, kg = lane >> 4;

  f32x4 acc[4][4] = {};   // [ni][mi]

  const int srow = tid >> 3;
  const int scol = (tid & 7) * 8;
  const unsigned sdst = tid * 8;

  auto stage = [&](int buf, int kt) {
#pragma unroll
    for (int i = 0; i < 4; ++i) {
      __builtin_amdgcn_global_load_lds(
          (glob_u32*)(A  + (size_t)(tm * 128 + i * 32 + srow) * DD + kt * 64 + scol),
          (lds_u32*)&Al[buf][i * 2048 + sdst], 16, 0, 0);
      __builtin_amdgcn_global_load_lds(
          (glob_u32*)(Bt + (size_t)(tn * 128 + i * 32 + srow) * DD + kt * 64 + scol),
          (lds_u32*)&Bl[buf][i * 2048 + sdst], 16, 0, 0);
    }
  };

  stage(0, 0);
  __syncthreads();

  for (int kt = 0; kt < 16; ++kt) {
    const int buf = kt & 1;
    if (kt < 15) stage(buf ^ 1, kt + 1);
#pragma unroll
    for (int ks = 0; ks < 2; ++ks) {
      bf16x8 af[4], bfr[4];
#pragma unroll
      for (int mi = 0; mi < 4; ++mi)
        af[mi] = *(const bf16x8*)&Al[buf][(wr * 64 + mi * 16 + l15) * 64 + ks * 32 + kg * 8];
#pragma unroll
      for (int ni = 0; ni < 4; ++ni)
        bfr[ni] = *(const bf16x8*)&Bl[buf][(wc * 64 + ni * 16 + l15) * 64 + ks * 32 + kg * 8];
#pragma unroll
      for (int mi = 0; mi < 4; ++mi)
#pragma unroll
        for (int ni = 0; ni < 4; ++ni)
          acc[ni][mi] = __builtin_amdgcn_mfma_f32_16x16x32_bf16(bfr[ni], af[mi], acc[ni][mi], 0, 0, 0);
    }
    __syncthreads();
  }

  // C-store: row = m (l15), 4 consecutive n-cols per acc (kg*4+j) -> 8B stores
#pragma unroll
  for (int mi = 0; mi < 4; ++mi) {
    const size_t row = (size_t)tm * 128 + wr * 64 + mi * 16 + l15;
#pragma unroll
    for (int ni = 0; ni < 4; ++ni) {
      const size_t col = (size_t)tn * 128 + wc * 64 + ni * 16 + kg * 4;
      us4 v;
      v[0] = f2bf(acc[ni][mi][0]); v[1] = f2bf(acc[ni][mi][1]);
      v[2] = f2bf(acc[ni][mi][2]); v[3] = f2bf(acc[ni][mi][3]);
      *(us4*)(C + row * NZ + col) = v;
    }
  }
}

// ---------------- scan: 256 steps, distributed-flag group barrier
// 256 blocks x 256 threads, 1/CU. group g = blk&7 (XCD-local), sb = blk>>3.
// Block owns batch rows [g*16,g*16+16) x hidden cols [sb*32,sb*32+32).
// flags[g*64 + sb] = number of h versions this block has published.
__global__ __launch_bounds__(256, 1) void k_scan(const float* __restrict__ init_cs,
                                                 const int* __restrict__ masks,
                                                 const unsigned short* __restrict__ WhT,
                                                 const float* __restrict__ bias,
                                                 const unsigned short* __restrict__ xz,
                                                 float* __restrict__ out,
                                                 unsigned short* __restrict__ hglob,
                                                 unsigned* __restrict__ flags) {
  __shared__ char  hlds_c[32768];               // 32KB h tile (swizzled layout)
  __shared__ float zlds[4][16][33];
  __shared__ int   mlds[TT * 16 + 16];          // masks [t][er], +pad

  const int tid = threadIdx.x;
  const int wave = tid >> 6, lane = tid & 63;
  const int l15 = lane & 15, kg = lane >> 4;
  const int blk = blockIdx.x;
  const int g = blk & 7;
  const int sb = blk >> 3;
  const int u0 = sb * 32;
  const int row0 = g * 16;
  unsigned* fl = flags + g * 64;                // 256B stride per group

  // ---- Wh fragments resident in registers, pinned (AGPR/VGPR unified file)
  u32x4 w0[32], w1[32];
  {
    const size_t r0 = (size_t)(wave * UU + u0 + l15) * DD;
    const size_t r1 = (size_t)(wave * UU + u0 + 16 + l15) * DD;
#pragma unroll
    for (int ks = 0; ks < 32; ++ks) {
      w0[ks] = *(const u32x4*)(WhT + r0 + ks * 32 + kg * 8);
      w1[ks] = *(const u32x4*)(WhT + r1 + ks * 32 + kg * 8);
    }
#pragma unroll
    for (int ks = 0; ks < 32; ++ks) {
      asm volatile("" : "+v"(w0[ks]));
      asm volatile("" : "+v"(w1[ks]));
    }
  }

  // ---- stage masks to LDS: mlds[t*16+er] = masks[t][row0+er]
  for (int i = 0; i < 16; ++i) {
    int idx = i * 256 + tid;
    mlds[idx] = masks[(size_t)(idx >> 4) * BB + row0 + (idx & 15)];
  }
  if (tid < 16) mlds[TT * 16 + tid] = 0;

  const int er = tid >> 4;
  const int ec = (tid & 15) * 2;
  const int grow = row0 + er;
  const int guu = u0 + ec;

  float bs0[4], bs1[4];
#pragma unroll
  for (int gt = 0; gt < 4; ++gt) {
    bs0[gt] = bias[gt * UU + guu];
    bs1[gt] = bias[gt * UU + guu + 1];
  }

  float cv0 = init_cs[(size_t)grow * UU + guu];
  float cv1 = init_cs[(size_t)grow * UU + guu + 1];
  float hv0 = init_cs[(size_t)BB * UU + grow * UU + guu];
  float hv1 = init_cs[(size_t)BB * UU + grow * UU + guu + 1];

  const unsigned wswz = ((unsigned)(er & 7)) << 4;
  const unsigned hoff = (unsigned)er * 2048u + ((((unsigned)guu) * 2u) ^ wswz);

  { // publish h(0) (masked) into buf 0
    int m0 = masks[grow];                        // masks[0][grow]
    float s = m0 ? 0.f : 1.f;
    char* base = (char*)hglob + (size_t)g * 32768 + hoff;
    unsigned pv = ((unsigned)f2bf(hv1 * s) << 16) | f2bf(hv0 * s);
    *(unsigned*)base = pv;
  }
  __syncthreads();                               // drain h(0) stores (vmcnt0)
  if (tid == 0) fl[sb] = 1;
  if (wave == 0) {
    unsigned v;
    do { v = __hip_atomic_load(&fl[lane & 31], __ATOMIC_RELAXED, __HIP_MEMORY_SCOPE_AGENT); }
    while (!__all(v >= 1));
  }
  __syncthreads();

  // swizzled A-frag base pointers (XOR bank swizzle bits 4-6)
  const unsigned rswz = ((unsigned)(l15 & 7)) << 4;
  const char* hp0 = hlds_c + l15 * 2048 + (((unsigned)(kg * 16 + 0)) ^ rswz);
  const char* hp1 = hlds_c + l15 * 2048 + (((unsigned)(kg * 16 + 64)) ^ rswz);

  for (int t = 0; t < TT; ++t) {
    // --- stage h(t): asm sc0 dwordx4 -> regs -> LDS (round-5-proven)
    {
      const char* gsrc = (const char*)hglob + ((size_t)((t & 1) * 8 + g)) * 32768;
      u32x4 sv[8];
#pragma unroll
      for (int i = 0; i < 8; ++i) {
        const char* ap = gsrc + (i * 256 + tid) * 16;
        asm volatile("global_load_dwordx4 %0, %1, off sc0" : "=v"(sv[i]) : "v"(ap));
      }
      asm volatile("s_waitcnt vmcnt(0)" ::: "memory");
      __builtin_amdgcn_sched_barrier(0);
#pragma unroll
      for (int i = 0; i < 8; ++i)
        *(u32x4*)(hlds_c + (i * 256 + tid) * 16) = sv[i];
    }
    __syncthreads();

    // --- xz(t) loads issued here: latency hides under the MFMA phase,
    //     drained by the zlds __syncthreads (post-MFMA), used after it.
    unsigned xzv[4];
    {
      const size_t xrow = ((size_t)(t * BB + grow)) * NZ;
#pragma unroll
      for (int gt = 0; gt < 4; ++gt)
        xzv[gt] = *(const unsigned*)(xz + xrow + gt * UU + guu);
    }

    // --- z = h @ Wh (this wave's gate, 32 z-cols x 16 rows)
    f32x4 acc0 = {0.f, 0.f, 0.f, 0.f};
    f32x4 acc1 = {0.f, 0.f, 0.f, 0.f};
#pragma unroll
    for (int ks = 0; ks < 32; ++ks) {
      const char* p = ((ks & 1) ? hp1 : hp0) + (ks >> 1) * 128;
      bf16x8 a = *(const bf16x8*)p;
      acc0 = __builtin_amdgcn_mfma_f32_16x16x32_bf16(a, __builtin_bit_cast(bf16x8, w0[ks]), acc0, 0, 0, 0);
      acc1 = __builtin_amdgcn_mfma_f32_16x16x32_bf16(a, __builtin_bit_cast(bf16x8, w1[ks]), acc1, 0, 0, 0);
    }

    // --- exchange gates across waves via LDS
#pragma unroll
    for (int j = 0; j < 4; ++j) {
      zlds[wave][kg * 4 + j][l15] = acc0[j];
      zlds[wave][kg * 4 + j][16 + l15] = acc1[j];
    }
    __syncthreads();

    // --- gate math
    const int mcur = mlds[t * 16 + er];
    const int mnxt = mlds[(t + 1) * 16 + er];
    float z0[4], z1[4];
#pragma unroll
    for (int gt = 0; gt < 4; ++gt) {
      z0[gt] = zlds[gt][er][ec]     + bs0[gt] + bf2f((unsigned short)(xzv[gt] & 0xffffu));
      z1[gt] = zlds[gt][er][ec + 1] + bs1[gt] + bf2f((unsigned short)(xzv[gt] >> 16));
    }
    const float sm = mcur ? 0.f : 1.f;
    cv0 *= sm; cv1 *= sm;
    {
      float ig = sigm(z0[0]), fg = sigm(z0[1]), og = sigm(z0[2]), ug = tanh_(z0[3]);
      cv0 = fg * cv0 + ig * ug;
      hv0 = og * tanh_(cv0);
    }
    {
      float ig = sigm(z1[0]), fg = sigm(z1[1]), og = sigm(z1[2]), ug = tanh_(z1[3]);
      cv1 = fg * cv1 + ig * ug;
      hv1 = og * tanh_(cv1);
    }

    // --- out + publish h(t+1) (masked) into buf (t+1)&1
    *(f32x2*)(out + (size_t)t * (BB * UU) + (size_t)grow * UU + guu) = (f32x2){hv0, hv1};
    {
      const float sn = mnxt ? 0.f : 1.f;
      char* hdst = (char*)hglob + ((size_t)(((t + 1) & 1) * 8 + g)) * 32768 + hoff;
      unsigned pv = ((unsigned)f2bf(hv1 * sn) << 16) | f2bf(hv0 * sn);
      *(unsigned*)hdst = pv;
    }
    __syncthreads();                             // drain stores (vmcnt0/wave)
    if (tid == 0) fl[sb] = (unsigned)(t + 2);    // publish
    if (wave == 0) {                             // parallel poll: all 32 slots
      const unsigned tgt = (unsigned)(t + 2);
      unsigned v;
      do { v = __hip_atomic_load(&fl[lane & 31], __ATOMIC_RELAXED, __HIP_MEMORY_SCOPE_AGENT); }
      while (!__all(v >= tgt));
    }
    __syncthreads();
  }

  // final states: [c ; h] appended after out
  float* so = out + (size_t)TT * BB * UU;
  *(f32x2*)(so + (size_t)grow * UU + guu) = (f32x2){cv0, cv1};
  *(f32x2*)(so + (size_t)BB * UU + grow * UU + guu) = (f32x2){hv0, hv1};
}

// ---------------------------------------------------------------------------
extern "C" void kernel_launch(void* const* d_in, const int* in_sizes, int n_in,
                              void* d_out, int out_size, void* d_ws, size_t ws_size,
                              hipStream_t stream) {
  const float* inputs  = (const float*)d_in[0];  // [256][128][1024]
  const float* states  = (const float*)d_in[1];  // [2][128][1024]
  const int*   masks   = (const int*)d_in[2];    // [256][128]
  const float* kernelx = (const float*)d_in[3];  // [1024][4096]
  const float* kernelh = (const float*)d_in[4];  // [1024][4096]
  const float* bias    = (const float*)d_in[5];  // [4096]
  float* out = (float*)d_out;
  char* ws = (char*)d_ws;

  unsigned* flags       = (unsigned*)ws;                                 // 2KB
  unsigned short* hglob = (unsigned short*)(ws + 65536);                 // 512KB
  unsigned short* WhT   = (unsigned short*)(ws + (size_t)2  * 1048576);  // 8MB
  unsigned short* WxT   = (unsigned short*)(ws + (size_t)10 * 1048576);  // 8MB
  unsigned short* Abf   = (unsigned short*)(ws + (size_t)18 * 1048576);  // 64MB
  unsigned short* xzbig = (unsigned short*)(ws + (size_t)82 * 1048576);  // 256MB

  k_transpose<<<dim3(64, 16), dim3(256), 0, stream>>>(kernelx, WxT);
  k_transpose<<<dim3(64, 16), dim3(256), 0, stream>>>(kernelh, WhT);
  k_convert<<<dim3(16384), dim3(256), 0, stream>>>(inputs, Abf, (TT * BB * DD) / 8);
  k_gemm_bf<<<dim3(8192), dim3(256), 0, stream>>>(Abf, WxT, xzbig);
  hipMemsetAsync(flags, 0, 2048, stream);
  k_scan<<<dim3(256), dim3(256), 0, stream>>>(states, masks, WhT, bias, xzbig,
                                              out, hglob, flags);
}

// Round 8
// 1195.365 us; speedup vs baseline: 5.1264x; 1.0342x over previous
//
#include <hip/hip_runtime.h>

// ---------------------------------------------------------------------------
// LSTM: out[t] = h_t for t in [0,256);  final (c,h) appended.
//   T=256, B=128, D=1024, U=1024, 4U=4096
// Pipeline (ws ~338MB):
//   k_convert   : inputs f32 -> bf16
//   k_transpose : kernelx/kernelh f32 [1024][4096] -> W^T bf16 [4096][1024]
//   k_gemm_bf   : xz = inputs_bf @ kernelx (m97 structure, unchanged)
//   k_scan      : single launch, 256 steps, 256 blocks = 256 CUs, 1/CU;
//                 8 groups x 32 blocks (g = blk&7, XCD-local).
//                 NEW: quarter-pipelined h staging (counted vmcnt, raw
//                 barriers; MFMA q hides stage of q+1..3) + counted publish
//                 (h-store acked via vmcnt(1); out-store stays in flight).
//                 Flag barrier protocol unchanged from round 7.
// ---------------------------------------------------------------------------

typedef float  f32x4 __attribute__((ext_vector_type(4)));
typedef float  f32x2 __attribute__((ext_vector_type(2)));
typedef __bf16 bf16x8 __attribute__((ext_vector_type(8)));
typedef unsigned short us8 __attribute__((ext_vector_type(8)));
typedef unsigned short us4 __attribute__((ext_vector_type(4)));
typedef unsigned int   u32x4 __attribute__((ext_vector_type(4)));

#define TT 256
#define BB 128
#define DD 1024
#define UU 1024
#define NZ 4096

typedef __attribute__((address_space(3))) unsigned       lds_u32;
typedef const __attribute__((address_space(1))) unsigned glob_u32;

__device__ __forceinline__ unsigned short f2bf(float x) {
  union { float f; unsigned u; } v; v.f = x;
  unsigned r = v.u + 0x7fffu + ((v.u >> 16) & 1u);   // RNE
  return (unsigned short)(r >> 16);
}
__device__ __forceinline__ float bf2f(unsigned short b) {
  union { unsigned u; float f; } v; v.u = ((unsigned)b) << 16;
  return v.f;
}
__device__ __forceinline__ float sigm(float x) { return 1.f / (1.f + __expf(-x)); }
__device__ __forceinline__ float tanh_(float x) { return 1.f - 2.f / (__expf(2.f * x) + 1.f); }

// ---------------- f32 -> bf16 bulk convert (8 elems/thread)
__global__ __launch_bounds__(256) void k_convert(const float* __restrict__ in,
                                                 unsigned short* __restrict__ out,
                                                 int n8) {
  int i = blockIdx.x * 256 + threadIdx.x;
  if (i >= n8) return;
  const float4 a = *(const float4*)(in + (size_t)i * 8);
  const float4 b = *(const float4*)(in + (size_t)i * 8 + 4);
  us8 v;
  v[0] = f2bf(a.x); v[1] = f2bf(a.y); v[2] = f2bf(a.z); v[3] = f2bf(a.w);
  v[4] = f2bf(b.x); v[5] = f2bf(b.y); v[6] = f2bf(b.z); v[7] = f2bf(b.w);
  *(us8*)(out + (size_t)i * 8) = v;
}

// ---------------- transpose+convert: in f32 [1024][4096] -> out bf16 [4096][1024]
__global__ __launch_bounds__(256) void k_transpose(const float* __restrict__ in,
                                                   unsigned short* __restrict__ out) {
  __shared__ unsigned short tile[64][72];
  const int ni = blockIdx.x;
  const int ki = blockIdx.y;
  const int t = threadIdx.x;
  const int c = t & 63, r0 = t >> 6;
#pragma unroll
  for (int rr = 0; rr < 16; ++rr) {
    int r = r0 * 16 + rr;
    tile[r][c] = f2bf(in[(size_t)(ki * 64 + r) * NZ + ni * 64 + c]);
  }
  __syncthreads();
  const int kcol = t & 63, ng = t >> 6;
#pragma unroll
  for (int cc = 0; cc < 16; ++cc) {
    int n_off = ng * 16 + cc;
    out[(size_t)(ni * 64 + n_off) * DD + ki * 64 + kcol] = tile[kcol][n_off];
  }
}

// ---------------- xz = A_bf16[32768][1024] @ WxT^T, m97 structure (unchanged)
__global__ __launch_bounds__(256, 2) void k_gemm_bf(const unsigned short* __restrict__ A,
                                                    const unsigned short* __restrict__ Bt,
                                                    unsigned short* __restrict__ C) {
  __shared__ unsigned short Al[2][128 * 64];
  __shared__ unsigned short Bl[2][128 * 64];
  const int bx = blockIdx.x;
  const int wgid = (bx & 7) * 1024 + (bx >> 3);
  const int tm = wgid >> 5, tn = wgid & 31;
  const int tid = threadIdx.x;
  const int wave = tid >> 6, lane = tid & 63;
  const int wr = wave >> 1, wc = wave & 1;
  const int l15 = lane & 15, kg = lane >> 4;

  f32x4 acc[4][4] = {};   // [ni][mi]

  const int srow = tid >> 3;
  const int scol = (tid & 7) * 8;
  const unsigned sdst = tid * 8;

  auto stage = [&](int buf, int kt) {
#pragma unroll
    for (int i = 0; i < 4; ++i) {
      __builtin_amdgcn_global_load_lds(
          (glob_u32*)(A  + (size_t)(tm * 128 + i * 32 + srow) * DD + kt * 64 + scol),
          (lds_u32*)&Al[buf][i * 2048 + sdst], 16, 0, 0);
      __builtin_amdgcn_global_load_lds(
          (glob_u32*)(Bt + (size_t)(tn * 128 + i * 32 + srow) * DD + kt * 64 + scol),
          (lds_u32*)&Bl[buf][i * 2048 + sdst], 16, 0, 0);
    }
  };

  stage(0, 0);
  __syncthreads();

  for (int kt = 0; kt < 16; ++kt) {
    const int buf = kt & 1;
    if (kt < 15) stage(buf ^ 1, kt + 1);
#pragma unroll
    for (int ks = 0; ks < 2; ++ks) {
      bf16x8 af[4], bfr[4];
#pragma unroll
      for (int mi = 0; mi < 4; ++mi)
        af[mi] = *(const bf16x8*)&Al[buf][(wr * 64 + mi * 16 + l15) * 64 + ks * 32 + kg * 8];
#pragma unroll
      for (int ni = 0; ni < 4; ++ni)
        bfr[ni] = *(const bf16x8*)&Bl[buf][(wc * 64 + ni * 16 + l15) * 64 + ks * 32 + kg * 8];
#pragma unroll
      for (int mi = 0; mi < 4; ++mi)
#pragma unroll
        for (int ni = 0; ni < 4; ++ni)
          acc[ni][mi] = __builtin_amdgcn_mfma_f32_16x16x32_bf16(bfr[ni], af[mi], acc[ni][mi], 0, 0, 0);
    }
    __syncthreads();
  }

#pragma unroll
  for (int mi = 0; mi < 4; ++mi) {
    const size_t row = (size_t)tm * 128 + wr * 64 + mi * 16 + l15;
#pragma unroll
    for (int ni = 0; ni < 4; ++ni) {
      const size_t col = (size_t)tn * 128 + wc * 64 + ni * 16 + kg * 4;
      us4 v;
      v[0] = f2bf(acc[ni][mi][0]); v[1] = f2bf(acc[ni][mi][1]);
      v[2] = f2bf(acc[ni][mi][2]); v[3] = f2bf(acc[ni][mi][3]);
      *(us4*)(C + row * NZ + col) = v;
    }
  }
}

// ---------------- scan: 256 steps, quarter-pipelined staging + counted publish
// One quarter = k-bytes [q*512, q*512+512) of all 16 rows (8KB).
// sv[2q],sv[2q+1] = rows 0-7 / 8-15 portions of quarter q.
#define SCAN_QUARTER(Q, VMSTR)                                                  \
  {                                                                             \
    asm volatile("s_waitcnt " VMSTR ::: "memory");                              \
    __builtin_amdgcn_sched_barrier(0);                                          \
    *(u32x4*)(hlds_c + sbase + (Q) * 512)         = sv[(Q) * 2];                \
    *(u32x4*)(hlds_c + sbase + 16384 + (Q) * 512) = sv[(Q) * 2 + 1];            \
    asm volatile("s_waitcnt lgkmcnt(0)" ::: "memory");                          \
    __builtin_amdgcn_sched_barrier(0);                                          \
    __builtin_amdgcn_s_barrier();                                               \
    _Pragma("unroll")                                                           \
    for (int ks = (Q) * 8; ks < (Q) * 8 + 8; ++ks) {                            \
      const char* p = ((ks & 1) ? hp1 : hp0) + (ks >> 1) * 128;                 \
      bf16x8 a = *(const bf16x8*)p;                                             \
      acc0 = __builtin_amdgcn_mfma_f32_16x16x32_bf16(a, __builtin_bit_cast(bf16x8, w0[ks]), acc0, 0, 0, 0); \
      acc1 = __builtin_amdgcn_mfma_f32_16x16x32_bf16(a, __builtin_bit_cast(bf16x8, w1[ks]), acc1, 0, 0, 0); \
    }                                                                           \
  }

__global__ __launch_bounds__(256, 1) void k_scan(const float* __restrict__ init_cs,
                                                 const int* __restrict__ masks,
                                                 const unsigned short* __restrict__ WhT,
                                                 const float* __restrict__ bias,
                                                 const unsigned short* __restrict__ xz,
                                                 float* __restrict__ out,
                                                 unsigned short* __restrict__ hglob,
                                                 unsigned* __restrict__ flags) {
  __shared__ char  hlds_c[32768];               // 32KB h tile (swizzled layout)
  __shared__ float zlds[4][16][33];
  __shared__ int   mlds[TT * 16 + 16];          // masks [t][er], +pad

  const int tid = threadIdx.x;
  const int wave = tid >> 6, lane = tid & 63;
  const int l15 = lane & 15, kg = lane >> 4;
  const int blk = blockIdx.x;
  const int g = blk & 7;
  const int sb = blk >> 3;
  const int u0 = sb * 32;
  const int row0 = g * 16;
  unsigned* fl = flags + g * 64;                // 256B stride per group

  // ---- Wh fragments resident in registers, pinned
  u32x4 w0[32], w1[32];
  {
    const size_t r0 = (size_t)(wave * UU + u0 + l15) * DD;
    const size_t r1 = (size_t)(wave * UU + u0 + 16 + l15) * DD;
#pragma unroll
    for (int ks = 0; ks < 32; ++ks) {
      w0[ks] = *(const u32x4*)(WhT + r0 + ks * 32 + kg * 8);
      w1[ks] = *(const u32x4*)(WhT + r1 + ks * 32 + kg * 8);
    }
#pragma unroll
    for (int ks = 0; ks < 32; ++ks) {
      asm volatile("" : "+v"(w0[ks]));
      asm volatile("" : "+v"(w1[ks]));
    }
  }

  // ---- stage masks to LDS: mlds[t*16+er] = masks[t][row0+er]
  for (int i = 0; i < 16; ++i) {
    int idx = i * 256 + tid;
    mlds[idx] = masks[(size_t)(idx >> 4) * BB + row0 + (idx & 15)];
  }
  if (tid < 16) mlds[TT * 16 + tid] = 0;

  const int er = tid >> 4;
  const int ec = (tid & 15) * 2;
  const int grow = row0 + er;
  const int guu = u0 + ec;

  float bs0[4], bs1[4];
#pragma unroll
  for (int gt = 0; gt < 4; ++gt) {
    bs0[gt] = bias[gt * UU + guu];
    bs1[gt] = bias[gt * UU + guu + 1];
  }

  float cv0 = init_cs[(size_t)grow * UU + guu];
  float cv1 = init_cs[(size_t)grow * UU + guu + 1];
  float hv0 = init_cs[(size_t)BB * UU + grow * UU + guu];
  float hv1 = init_cs[(size_t)BB * UU + grow * UU + guu + 1];

  const unsigned wswz = ((unsigned)(er & 7)) << 4;
  const unsigned hoff = (unsigned)er * 2048u + ((((unsigned)guu) * 2u) ^ wswz);

  { // publish h(0) (masked) into buf 0
    int m0 = masks[grow];                        // masks[0][grow]
    float s = m0 ? 0.f : 1.f;
    char* base = (char*)hglob + (size_t)g * 32768 + hoff;
    unsigned pv = ((unsigned)f2bf(hv1 * s) << 16) | f2bf(hv0 * s);
    *(unsigned*)base = pv;
  }
  __syncthreads();                               // full drain (prologue only)
  if (tid == 0) fl[sb] = 1;
  if (wave == 0) {
    unsigned v;
    do { v = __hip_atomic_load(&fl[lane & 31], __ATOMIC_RELAXED, __HIP_MEMORY_SCOPE_AGENT); }
    while (!__all(v >= 1));
  }
  __syncthreads();

  // swizzled A-frag base pointers (XOR bank swizzle bits 4-6)
  const unsigned rswz = ((unsigned)(l15 & 7)) << 4;
  const char* hp0 = hlds_c + l15 * 2048 + (((unsigned)(kg * 16 + 0)) ^ rswz);
  const char* hp1 = hlds_c + l15 * 2048 + (((unsigned)(kg * 16 + 64)) ^ rswz);

  // staging address: row = tid>>5 (j=0) / 8+(tid>>5) (j=1), 16B chunk tid&31
  const unsigned sbase = ((unsigned)(tid >> 5)) * 2048u + ((unsigned)(tid & 31)) * 16u;

  for (int t = 0; t < TT; ++t) {
    const char* gsrc = (const char*)hglob + ((size_t)((t & 1) * 8 + g)) * 32768;

    // --- issue all 8 stage loads, quarter order (q0j0,q0j1,q1j0,...)
    u32x4 sv[8];
#pragma unroll
    for (int q = 0; q < 4; ++q) {
#pragma unroll
      for (int j = 0; j < 2; ++j) {
        const char* ap = gsrc + sbase + j * 16384 + q * 512;
        asm volatile("global_load_dwordx4 %0, %1, off sc0" : "=v"(sv[q * 2 + j]) : "v"(ap));
      }
    }

    f32x4 acc0 = {0.f, 0.f, 0.f, 0.f};
    f32x4 acc1 = {0.f, 0.f, 0.f, 0.f};

    SCAN_QUARTER(0, "vmcnt(6)")
    SCAN_QUARTER(1, "vmcnt(4)")

    // --- xz(t) loads issued mid-pipeline: hidden under q2/q3 MFMA,
    //     drained by the zlds __syncthreads, used after it.
    unsigned xzv[4];
    {
      const size_t xrow = ((size_t)(t * BB + grow)) * NZ;
#pragma unroll
      for (int gt = 0; gt < 4; ++gt)
        xzv[gt] = *(const unsigned*)(xz + xrow + gt * UU + guu);
    }

    SCAN_QUARTER(2, "vmcnt(6)")   // retires l4,l5 (xz stays in flight)
    SCAN_QUARTER(3, "vmcnt(4)")   // retires l6,l7

    // --- exchange gates across waves via LDS
#pragma unroll
    for (int j = 0; j < 4; ++j) {
      zlds[wave][kg * 4 + j][l15] = acc0[j];
      zlds[wave][kg * 4 + j][16 + l15] = acc1[j];
    }
    __syncthreads();                             // drains lgkm + xz loads

    // --- gate math
    const int mcur = mlds[t * 16 + er];
    const int mnxt = mlds[(t + 1) * 16 + er];
    float z0[4], z1[4];
#pragma unroll
    for (int gt = 0; gt < 4; ++gt) {
      z0[gt] = zlds[gt][er][ec]     + bs0[gt] + bf2f((unsigned short)(xzv[gt] & 0xffffu));
      z1[gt] = zlds[gt][er][ec + 1] + bs1[gt] + bf2f((unsigned short)(xzv[gt] >> 16));
    }
    const float sm = mcur ? 0.f : 1.f;
    cv0 *= sm; cv1 *= sm;
    {
      float ig = sigm(z0[0]), fg = sigm(z0[1]), og = sigm(z0[2]), ug = tanh_(z0[3]);
      cv0 = fg * cv0 + ig * ug;
      hv0 = og * tanh_(cv0);
    }
    {
      float ig = sigm(z1[0]), fg = sigm(z1[1]), og = sigm(z1[2]), ug = tanh_(z1[3]);
      cv1 = fg * cv1 + ig * ug;
      hv1 = og * tanh_(cv1);
    }

    // --- counted publish: h store FIRST (L2), out store SECOND (stays in
    //     flight across the step boundary); vmcnt(1) = h acked.
    {
      const float sn = mnxt ? 0.f : 1.f;
      char* hdst = (char*)hglob + ((size_t)(((t + 1) & 1) * 8 + g)) * 32768 + hoff;
      unsigned pv = ((unsigned)f2bf(hv1 * sn) << 16) | f2bf(hv0 * sn);
      asm volatile("global_store_dword %0, %1, off" :: "v"(hdst), "v"(pv) : "memory");
      float* odst = out + (size_t)t * (BB * UU) + (size_t)grow * UU + guu;
      f32x2 ov = {hv0, hv1};
      asm volatile("global_store_dwordx2 %0, %1, off" :: "v"(odst), "v"(ov) : "memory");
    }
    asm volatile("s_waitcnt vmcnt(1)" ::: "memory");
    __builtin_amdgcn_sched_barrier(0);
    __builtin_amdgcn_s_barrier();                // all waves' h stores acked
    if (tid == 0) fl[sb] = (unsigned)(t + 2);    // publish step count
    if (wave == 0) {                             // parallel poll: all 32 slots
      const unsigned tgt = (unsigned)(t + 2);
      unsigned v;
      do { v = __hip_atomic_load(&fl[lane & 31], __ATOMIC_RELAXED, __HIP_MEMORY_SCOPE_AGENT); }
      while (!__all(v >= tgt));
    }
    __builtin_amdgcn_s_barrier();
  }

  // final states: [c ; h] appended after out
  float* so = out + (size_t)TT * BB * UU;
  *(f32x2*)(so + (size_t)grow * UU + guu) = (f32x2){cv0, cv1};
  *(f32x2*)(so + (size_t)BB * UU + grow * UU + guu) = (f32x2){hv0, hv1};
}

// ---------------------------------------------------------------------------
extern "C" void kernel_launch(void* const* d_in, const int* in_sizes, int n_in,
                              void* d_out, int out_size, void* d_ws, size_t ws_size,
                              hipStream_t stream) {
  const float* inputs  = (const float*)d_in[0];  // [256][128][1024]
  const float* states  = (const float*)d_in[1];  // [2][128][1024]
  const int*   masks   = (const int*)d_in[2];    // [256][128]
  const float* kernelx = (const float*)d_in[3];  // [1024][4096]
  const float* kernelh = (const float*)d_in[4];  // [1024][4096]
  const float* bias    = (const float*)d_in[5];  // [4096]
  float* out = (float*)d_out;
  char* ws = (char*)d_ws;

  unsigned* flags       = (unsigned*)ws;                                 // 2KB
  unsigned short* hglob = (unsigned short*)(ws + 65536);                 // 512KB
  unsigned short* WhT   = (unsigned short*)(ws + (size_t)2  * 1048576);  // 8MB
  unsigned short* WxT   = (unsigned short*)(ws + (size_t)10 * 1048576);  // 8MB
  unsigned short* Abf   = (unsigned short*)(ws + (size_t)18 * 1048576);  // 64MB
  unsigned short* xzbig = (unsigned short*)(ws + (size_t)82 * 1048576);  // 256MB

  k_transpose<<<dim3(64, 16), dim3(256), 0, stream>>>(kernelx, WxT);
  k_transpose<<<dim3(64, 16), dim3(256), 0, stream>>>(kernelh, WhT);
  k_convert<<<dim3(16384), dim3(256), 0, stream>>>(inputs, Abf, (TT * BB * DD) / 8);
  k_gemm_bf<<<dim3(8192), dim3(256), 0, stream>>>(Abf, WxT, xzbig);
  hipMemsetAsync(flags, 0, 2048, stream);
  k_scan<<<dim3(256), dim3(256), 0, stream>>>(states, masks, WhT, bias, xzbig,
                                              out, hglob, flags);
}